// Round 1
// baseline (538.614 us; speedup 1.0000x reference)
//
#include <hip/hip_runtime.h>
#include <hip/hip_bf16.h>

#define B_ 32
#define S_ 512
#define H_ 768
#define NH_ 12
#define DH_ 64
#define EC_ 4
#define CAPN_ 8

using short8  = __attribute__((ext_vector_type(8))) short;
using floatx4 = __attribute__((ext_vector_type(4))) float;
using bf16 = __hip_bfloat16;

// async 16B global->LDS. LDS dest must be wave-uniform base + lane*16.
__device__ __forceinline__ void gl_lds16(const void* g, void* l) {
  __builtin_amdgcn_global_load_lds(
      (const __attribute__((address_space(1))) unsigned int*)g,
      (__attribute__((address_space(3))) unsigned int*)l, 16, 0, 0);
}

// ---------- kernel 1: partial sums over S (8 chunks of 64) + fp32->bf16 convert ----------
__global__ void k_mean_convert(const float* __restrict__ X, bf16* __restrict__ Xh,
                               float* __restrict__ partial) {
  int idx = blockIdx.x * 256 + threadIdx.x;          // (b,h) 0..24575
  int b = idx / H_, h = idx - b * H_;
  int s0 = blockIdx.y * 64;
  size_t base = ((size_t)b * S_ + s0) * H_ + h;
  float sum = 0.f;
#pragma unroll 8
  for (int s = 0; s < 64; ++s) {
    float v = X[base + (size_t)s * H_];
    Xh[base + (size_t)s * H_] = __float2bfloat16(v);
    sum += v;
  }
  partial[(size_t)blockIdx.y * (B_ * H_) + idx] = sum;
}

__global__ void k_mean_reduce(const float* __restrict__ partial, float* __restrict__ hmean) {
  int idx = blockIdx.x * 256 + threadIdx.x;
  float s = 0.f;
#pragma unroll
  for (int c = 0; c < 8; ++c) s += partial[(size_t)c * (B_ * H_) + idx];
  hmean[idx] = s * (1.f / 512.f);                    // 1/512 exact
}

// ---------- kernel 2: W[k][n] -> Wt[n][k] bf16, all 4 mats x 8 experts ----------
// grid (24,24,32) z = mat*8+e, block 256, 32x32 tiles
__global__ void k_wt(const float* __restrict__ Wq, const float* __restrict__ Wk,
                     const float* __restrict__ Wv, const float* __restrict__ Wo,
                     bf16* __restrict__ Wt) {
  __shared__ float tile[32][33];
  int z = blockIdx.z;
  const float* Wbase = (z < 8 ? Wq : z < 16 ? Wk : z < 24 ? Wv : Wo) + (size_t)(z & 7) * H_ * H_;
  int k0 = blockIdx.x * 32, n0 = blockIdx.y * 32;
  int tj = threadIdx.x & 31, ti = threadIdx.x >> 5;  // ti 0..7
#pragma unroll
  for (int r = 0; r < 4; ++r)
    tile[ti + r * 8][tj] = Wbase[(size_t)(k0 + ti + r * 8) * H_ + n0 + tj];
  __syncthreads();
  bf16* out = Wt + (size_t)z * H_ * H_;
#pragma unroll
  for (int r = 0; r < 4; ++r)
    out[(size_t)(n0 + ti + r * 8) * H_ + k0 + tj] = __float2bfloat16(tile[tj][ti + r * 8]);
}

// ---------- kernel 3: routing (1 block, 256 threads) ----------
__global__ void k_route(const float* __restrict__ hmean,
                        const float* __restrict__ Wsc, const float* __restrict__ bsc,
                        const float* __restrict__ Wsu, const float* __restrict__ bsu,
                        int* __restrict__ eidx) {
  __shared__ float logit[B_][8];
  __shared__ float pcmax[B_];
  __shared__ int rc_s[B_], ru_s[B_];
  int t = threadIdx.x;
  {
    int b = t >> 3, g = t & 7;                       // 32 seq x 8 gates
    const float* w = (g < 4) ? (Wsc + g) : (Wsu + (g - 4));
    float acc = (g < 4) ? bsc[g] : bsu[g - 4];
    const float* hm = hmean + (size_t)b * H_;
    for (int hh = 0; hh < H_; ++hh) acc += hm[hh] * w[hh * 4];
    logit[b][g] = acc;
  }
  __syncthreads();
  if (t < B_) {
    float m = logit[t][0]; int a = 0;                // first-max ties like jnp.argmax
    for (int e = 1; e < 4; ++e) if (logit[t][e] > m) { m = logit[t][e]; a = e; }
    float s = 0.f;
    for (int e = 0; e < 4; ++e) s += expf(logit[t][e] - m);
    pcmax[t] = 1.f / s;                              // softmax max prob
    rc_s[t] = a;
    float mu = logit[t][4]; int au = 0;
    for (int e = 1; e < 4; ++e) if (logit[t][4 + e] > mu) { mu = logit[t][4 + e]; au = e; }
    ru_s[t] = au;
  }
  __syncthreads();
  if (t == 0) {
    // stable descending selection (equal -> lower index first) == argsort(-p)
    bool used[B_], kept[B_];
    int cnt[EC_] = {0, 0, 0, 0};
    for (int i = 0; i < B_; ++i) used[i] = false;
    for (int i = 0; i < B_; ++i) {
      int best = 0; float bv = -1e30f;
      for (int j = 0; j < B_; ++j)
        if (!used[j] && pcmax[j] > bv) { bv = pcmax[j]; best = j; }
      used[best] = true;
      kept[best] = (++cnt[rc_s[best]] <= CAPN_);
    }
    for (int i = 0; i < B_; ++i)
      eidx[i] = kept[i] ? rc_s[i] : EC_ + ru_s[i];
  }
}

// ---------- GEMM: Y[m][n] = sum_k A[m][k]*Wt[n][k] + bias[n] ----------
// 128x128 tile, BK=64, 256 thr (4 waves of 64x64), XOR-swizzled LDS chunks.
// OMODE 0: bf16 out (QKV, bz=grid.z selects); OMODE 1: fp32 out.
template <int OMODE>
__global__ __launch_bounds__(256) void k_gemm(
    const bf16* __restrict__ A, const bf16* __restrict__ Wt,
    const float* __restrict__ bias0, const float* __restrict__ bias1,
    const float* __restrict__ bias2,
    void* out0, void* out1, void* out2,
    const int* __restrict__ eidx, int mat0) {
  __shared__ __align__(16) char lds[32768];          // A tile 16KB | B tile 16KB
  int bz = blockIdx.z;
  int b = blockIdx.y;
  int e = eidx[b];
  int mtile = blockIdx.x & 3, ntile = blockIdx.x >> 2;
  int m0 = mtile * 128, n0 = ntile * 128;
  const bf16* Ab = A + (size_t)b * S_ * H_;
  const bf16* Wb = Wt + (size_t)((mat0 + bz) * 8 + e) * H_ * H_;
  const float* bias = ((bz == 0) ? bias0 : (bz == 1) ? bias1 : bias2) + (size_t)e * H_;
  void* outp = (bz == 0) ? out0 : (bz == 1) ? out1 : out2;

  int t = threadIdx.x, lane = t & 63, w = t >> 6;
  int wm = (w & 1) * 64, wn = (w >> 1) * 64;
  int lm = lane & 15, lq = lane >> 4;

  floatx4 acc[4][4] = {};
  for (int kt = 0; kt < 12; ++kt) {
    __syncthreads();                                 // protect LDS vs prev iter readers
#pragma unroll
    for (int r = 0; r < 8; ++r) {                    // 2048 chunks of 16B
      int c = t + r * 256;
      const bf16* g;
      if (c < 1024) {
        int mm = c >> 3, pos = c & 7, kc = pos ^ (mm & 7);
        g = Ab + (size_t)(m0 + mm) * H_ + kt * 64 + kc * 8;
      } else {
        int c2 = c - 1024;
        int nn = c2 >> 3, pos = c2 & 7, kc = pos ^ (nn & 7);
        g = Wb + (size_t)(n0 + nn) * H_ + kt * 64 + kc * 8;
      }
      gl_lds16(g, lds + (size_t)c * 16);
    }
    __syncthreads();                                 // vmcnt drained before barrier
#pragma unroll
    for (int kf = 0; kf < 2; ++kf) {
      int kc = kf * 4 + lq;
      short8 af[4], bf[4];
#pragma unroll
      for (int mf = 0; mf < 4; ++mf) {
        int mm = wm + mf * 16 + lm;
        af[mf] = *(const short8*)(lds + ((size_t)(mm * 8 + (kc ^ (mm & 7)))) * 16);
      }
#pragma unroll
      for (int nf = 0; nf < 4; ++nf) {
        int nn = wn + nf * 16 + lm;
        bf[nf] = *(const short8*)(lds + 16384 + ((size_t)(nn * 8 + (kc ^ (nn & 7)))) * 16);
      }
#pragma unroll
      for (int mf = 0; mf < 4; ++mf)
#pragma unroll
        for (int nf = 0; nf < 4; ++nf)
          acc[mf][nf] = __builtin_amdgcn_mfma_f32_16x16x32_bf16(af[mf], bf[nf], acc[mf][nf], 0, 0, 0);
    }
  }
  // epilogue: C/D layout col=lane&15, row=quad*4+reg
#pragma unroll
  for (int mf = 0; mf < 4; ++mf) {
#pragma unroll
    for (int nf = 0; nf < 4; ++nf) {
      int n = n0 + wn + nf * 16 + lm;
      float bv = bias[n];
      int mrow = m0 + wm + mf * 16 + lq * 4;
      size_t rowbase = ((size_t)b * S_ + mrow) * H_ + n;
#pragma unroll
      for (int r = 0; r < 4; ++r) {
        float v = acc[mf][nf][r] + bv;
        if (OMODE == 0) ((bf16*)outp)[rowbase + (size_t)r * H_] = __float2bfloat16(v);
        else            ((float*)outp)[rowbase + (size_t)r * H_] = v;
      }
    }
  }
}

// ---------- kernel 5: V -> Vt chunk layout [b][h][s>>3][dh][8 s] ----------
// grid (8, NH, B), block 256
__global__ void k_vt(const bf16* __restrict__ V, bf16* __restrict__ Vt) {
  __shared__ __align__(16) unsigned short tile[64][72];
  int sb = blockIdx.x, h = blockIdx.y, b = blockIdx.z;
  int t = threadIdx.x;
  const unsigned short* src =
      (const unsigned short*)V + ((size_t)(b * S_ + sb * 64)) * H_ + h * DH_;
#pragma unroll
  for (int r = 0; r < 2; ++r) {
    int i = (t >> 3) + r * 32, j8 = t & 7;
    uint4 val = *(const uint4*)(src + (size_t)i * H_ + j8 * 8);
    *(uint4*)&tile[i][j8 * 8] = val;
  }
  __syncthreads();
  unsigned short* dst =
      (unsigned short*)Vt + ((size_t)((b * NH_ + h) * 64 + sb * 8)) * 512;
#pragma unroll
  for (int r = 0; r < 2; ++r) {
    int c = t + r * 256;                             // chunk = scl*64 + dh
    int scl = c >> 6, dh = c & 63;
    union { unsigned short u[8]; uint4 v4; } pk;
#pragma unroll
    for (int j = 0; j < 8; ++j) pk.u[j] = tile[scl * 8 + j][dh];
    *(uint4*)(dst + (size_t)c * 8) = pk.v4;
  }
}

// ---------- kernel 6: attention, one block per (32-row q-tile, h, b) ----------
__global__ __launch_bounds__(256) void k_attn(
    const bf16* __restrict__ Q, const bf16* __restrict__ K,
    const bf16* __restrict__ Vt, const float* __restrict__ mask,
    bf16* __restrict__ Ctx) {
  __shared__ __align__(16) char ldsQ[4096];
  __shared__ __align__(16) char ldsK[8192];
  __shared__ __align__(16) bf16 sc[32 * 520];        // pad 512->520 (stride 1040B, 16B-mult)
  __shared__ float inv_sum[32];

  int qt = blockIdx.x, h = blockIdx.y, b = blockIdx.z;
  int q0 = qt * 32;
  int t = threadIdx.x, lane = t & 63, w = t >> 6;
  int lm = lane & 15, lq = lane >> 4;

  {  // stage Q tile [32 s][64 dh], swizzled chunks
    int s = t >> 3, pos = t & 7, kc = pos ^ (s & 7);
    const bf16* g = Q + ((size_t)(b * S_ + q0 + s)) * H_ + h * DH_ + kc * 8;
    gl_lds16(g, ldsQ + (size_t)t * 16);
  }
  __syncthreads();

  short8 qf[2][2];                                   // loop-invariant A frags
#pragma unroll
  for (int mf = 0; mf < 2; ++mf)
#pragma unroll
    for (int kf = 0; kf < 2; ++kf) {
      int srow = mf * 16 + lm, kc = kf * 4 + lq;
      qf[mf][kf] = *(const short8*)(ldsQ + ((size_t)(srow * 8 + (kc ^ (srow & 7)))) * 16);
    }

  // phase 1: scores = Q K^T / 8 + mask -> sc (bf16)
  for (int kt = 0; kt < 8; ++kt) {
#pragma unroll
    for (int r = 0; r < 2; ++r) {
      int c = t + r * 256;
      int s = c >> 3, pos = c & 7, kc = pos ^ (s & 7);
      const bf16* g = K + ((size_t)(b * S_ + kt * 64 + s)) * H_ + h * DH_ + kc * 8;
      gl_lds16(g, ldsK + (size_t)c * 16);
    }
    __syncthreads();
    floatx4 a2[2] = {};
#pragma unroll
    for (int kf = 0; kf < 2; ++kf) {
      int row = w * 16 + lm, kc = kf * 4 + lq;
      short8 bfr = *(const short8*)(ldsK + ((size_t)(row * 8 + (kc ^ (row & 7)))) * 16);
#pragma unroll
      for (int mf = 0; mf < 2; ++mf)
        a2[mf] = __builtin_amdgcn_mfma_f32_16x16x32_bf16(qf[mf][kf], bfr, a2[mf], 0, 0, 0);
    }
    int col = kt * 64 + w * 16 + lm;
    float mv = mask[(size_t)b * S_ + col];
#pragma unroll
    for (int mf = 0; mf < 2; ++mf)
#pragma unroll
      for (int r = 0; r < 4; ++r) {
        int row = mf * 16 + lq * 4 + r;
        sc[row * 520 + col] = __float2bfloat16(a2[mf][r] * 0.125f + mv);
      }
    __syncthreads();
  }

  {  // softmax over each row of sc; P (unnormalized) back to sc, 1/sum saved
    int row = t >> 3, seg = t & 7;
    bf16* rp = sc + row * 520;
    float rm = -1e30f;
#pragma unroll 8
    for (int i = 0; i < 64; ++i) rm = fmaxf(rm, __bfloat162float(rp[seg + i * 8]));
    rm = fmaxf(rm, __shfl_xor(rm, 1));
    rm = fmaxf(rm, __shfl_xor(rm, 2));
    rm = fmaxf(rm, __shfl_xor(rm, 4));
    float sum = 0.f;
#pragma unroll 8
    for (int i = 0; i < 64; ++i) {
      float e = __expf(__bfloat162float(rp[seg + i * 8]) - rm);
      sum += e;
      rp[seg + i * 8] = __float2bfloat16(e);
    }
    sum += __shfl_xor(sum, 1);
    sum += __shfl_xor(sum, 2);
    sum += __shfl_xor(sum, 4);
    if (seg == 0) inv_sum[row] = 1.f / sum;
  }
  __syncthreads();

  // phase 2: ctx = P V from Vt chunks
  floatx4 oacc[2] = {};
  const bf16* vbase = Vt + ((size_t)(b * NH_ + h)) * 64 * 512;
  for (int kt = 0; kt < 8; ++kt) {
#pragma unroll
    for (int r = 0; r < 2; ++r) {
      int c = t + r * 256;
      gl_lds16(vbase + ((size_t)(kt * 512 + c)) * 8, ldsK + (size_t)c * 16);
    }
    __syncthreads();
#pragma unroll
    for (int kf = 0; kf < 2; ++kf) {
      int dh = w * 16 + lm;
      short8 bfr = *(const short8*)(ldsK + ((size_t)((kf * 4 + lq) * 64 + dh)) * 16);
#pragma unroll
      for (int mf = 0; mf < 2; ++mf) {
        int row = mf * 16 + lm;
        short8 af = *(const short8*)((const char*)sc +
                        ((size_t)(row * 520 + kt * 64 + kf * 32 + lq * 8)) * 2);
        oacc[mf] = __builtin_amdgcn_mfma_f32_16x16x32_bf16(af, bfr, oacc[mf], 0, 0, 0);
      }
    }
    __syncthreads();
  }
  int dh = w * 16 + lm;
#pragma unroll
  for (int mf = 0; mf < 2; ++mf)
#pragma unroll
    for (int r = 0; r < 4; ++r) {
      int row = mf * 16 + lq * 4 + r;
      float v = oacc[mf][r] * inv_sum[row];
      Ctx[((size_t)(b * S_ + q0 + row)) * H_ + h * DH_ + dh] = __float2bfloat16(v);
    }
}

extern "C" void kernel_launch(void* const* d_in, const int* in_sizes, int n_in,
                              void* d_out, int out_size, void* d_ws, size_t ws_size,
                              hipStream_t stream) {
  const float* X    = (const float*)d_in[0];
  const float* mask = (const float*)d_in[1];
  const float* Wq   = (const float*)d_in[2];
  const float* bq   = (const float*)d_in[3];
  const float* Wk   = (const float*)d_in[4];
  const float* bk   = (const float*)d_in[5];
  const float* Wv   = (const float*)d_in[6];
  const float* bv   = (const float*)d_in[7];
  const float* Wo   = (const float*)d_in[8];
  const float* bo   = (const float*)d_in[9];
  const float* Wsc  = (const float*)d_in[10];
  const float* bsc  = (const float*)d_in[11];
  const float* Wsu  = (const float*)d_in[12];
  const float* bsu  = (const float*)d_in[13];

  char* ws = (char*)d_ws;
  int*   eidx    = (int*)ws;                        //      128 B
  float* partial = (float*)(ws + 256);              //  786,432 B
  float* hmean   = (float*)(ws + 786688);           //   98,304 B
  bf16*  Xh      = (bf16*)(ws + 884992);            // 25,165,824 B
  bf16*  Wt      = (bf16*)(ws + 26050816);          // 37,748,736 B
  bf16*  qb      = (bf16*)(ws + 63799552);          // 25,165,824 B
  bf16*  kb      = (bf16*)(ws + 88965376);          // 25,165,824 B
  bf16*  vb      = (bf16*)(ws + 114131200);         // 25,165,824 B
  bf16*  Vt      = (bf16*)(ws + 139297024);         // 25,165,824 B -> 164,462,848 total
  bf16*  ctx     = Xh;                              // alias: Xh dead after QKV GEMM

  k_mean_convert<<<dim3(96, 8), 256, 0, stream>>>(X, Xh, partial);
  k_mean_reduce<<<96, 256, 0, stream>>>(partial, hmean);
  k_wt<<<dim3(24, 24, 32), 256, 0, stream>>>(Wq, Wk, Wv, Wo, Wt);
  k_route<<<1, 256, 0, stream>>>(hmean, Wsc, bsc, Wsu, bsu, eidx);
  k_gemm<0><<<dim3(24, 32, 3), 256, 0, stream>>>(Xh, Wt, bq, bk, bv,
                                                 (void*)qb, (void*)kb, (void*)vb, eidx, 0);
  k_vt<<<dim3(8, NH_, B_), 256, 0, stream>>>(vb, Vt);
  k_attn<<<dim3(16, NH_, B_), 256, 0, stream>>>(qb, kb, Vt, mask, ctx);
  k_gemm<1><<<dim3(24, 32, 1), 256, 0, stream>>>(ctx, Wt, bo, bo, bo,
                                                 d_out, d_out, d_out, eidx, 3);
}

// Round 2
// 498.749 us; speedup vs baseline: 1.0799x; 1.0799x over previous
//
#include <hip/hip_runtime.h>
#include <hip/hip_bf16.h>

#define B_ 32
#define S_ 512
#define H_ 768
#define NH_ 12
#define DH_ 64
#define EC_ 4
#define CAPN_ 8

using short8  = __attribute__((ext_vector_type(8))) short;
using floatx4 = __attribute__((ext_vector_type(4))) float;
using bf16 = __hip_bfloat16;

// async 16B global->LDS. LDS dest must be wave-uniform base + lane*16.
__device__ __forceinline__ void gl_lds16(const void* g, void* l) {
  __builtin_amdgcn_global_load_lds(
      (const __attribute__((address_space(1))) unsigned int*)g,
      (__attribute__((address_space(3))) unsigned int*)l, 16, 0, 0);
}

// ---------- kernel 1: partial sums over S (8 chunks of 64) + fp32->bf16 convert ----------
__global__ void k_mean_convert(const float* __restrict__ X, bf16* __restrict__ Xh,
                               float* __restrict__ partial) {
  int idx = blockIdx.x * 256 + threadIdx.x;          // (b,h) 0..24575
  int b = idx / H_, h = idx - b * H_;
  int s0 = blockIdx.y * 64;
  size_t base = ((size_t)b * S_ + s0) * H_ + h;
  float sum = 0.f;
#pragma unroll 8
  for (int s = 0; s < 64; ++s) {
    float v = X[base + (size_t)s * H_];
    Xh[base + (size_t)s * H_] = __float2bfloat16(v);
    sum += v;
  }
  partial[(size_t)blockIdx.y * (B_ * H_) + idx] = sum;
}

__global__ void k_mean_reduce(const float* __restrict__ partial, float* __restrict__ hmean) {
  int idx = blockIdx.x * 256 + threadIdx.x;
  float s = 0.f;
#pragma unroll
  for (int c = 0; c < 8; ++c) s += partial[(size_t)c * (B_ * H_) + idx];
  hmean[idx] = s * (1.f / 512.f);                    // 1/512 exact
}

// ---------- kernel 2: W[k][n] -> Wt[n][k] bf16, all 4 mats x 8 experts ----------
__global__ void k_wt(const float* __restrict__ Wq, const float* __restrict__ Wk,
                     const float* __restrict__ Wv, const float* __restrict__ Wo,
                     bf16* __restrict__ Wt) {
  __shared__ float tile[32][33];
  int z = blockIdx.z;
  const float* Wbase = (z < 8 ? Wq : z < 16 ? Wk : z < 24 ? Wv : Wo) + (size_t)(z & 7) * H_ * H_;
  int k0 = blockIdx.x * 32, n0 = blockIdx.y * 32;
  int tj = threadIdx.x & 31, ti = threadIdx.x >> 5;  // ti 0..7
#pragma unroll
  for (int r = 0; r < 4; ++r)
    tile[ti + r * 8][tj] = Wbase[(size_t)(k0 + ti + r * 8) * H_ + n0 + tj];
  __syncthreads();
  bf16* out = Wt + (size_t)z * H_ * H_;
#pragma unroll
  for (int r = 0; r < 4; ++r)
    out[(size_t)(n0 + ti + r * 8) * H_ + k0 + tj] = __float2bfloat16(tile[tj][ti + r * 8]);
}

// ---------- kernel 3: routing (1 block, 256 threads) ----------
__global__ void k_route(const float* __restrict__ hmean,
                        const float* __restrict__ Wsc, const float* __restrict__ bsc,
                        const float* __restrict__ Wsu, const float* __restrict__ bsu,
                        int* __restrict__ eidx) {
  __shared__ float logit[B_][8];
  __shared__ float pcmax[B_];
  __shared__ int rc_s[B_], ru_s[B_];
  int t = threadIdx.x;
  {
    int b = t >> 3, g = t & 7;                       // 32 seq x 8 gates
    const float* w = (g < 4) ? (Wsc + g) : (Wsu + (g - 4));
    float acc = (g < 4) ? bsc[g] : bsu[g - 4];
    const float* hm = hmean + (size_t)b * H_;
    for (int hh = 0; hh < H_; ++hh) acc += hm[hh] * w[hh * 4];
    logit[b][g] = acc;
  }
  __syncthreads();
  if (t < B_) {
    float m = logit[t][0]; int a = 0;                // first-max ties like jnp.argmax
    for (int e = 1; e < 4; ++e) if (logit[t][e] > m) { m = logit[t][e]; a = e; }
    float s = 0.f;
    for (int e = 0; e < 4; ++e) s += expf(logit[t][e] - m);
    pcmax[t] = 1.f / s;                              // softmax max prob
    rc_s[t] = a;
    float mu = logit[t][4]; int au = 0;
    for (int e = 1; e < 4; ++e) if (logit[t][4 + e] > mu) { mu = logit[t][4 + e]; au = e; }
    ru_s[t] = au;
  }
  __syncthreads();
  if (t == 0) {
    // stable descending selection (equal -> lower index first) == argsort(-p)
    bool used[B_], kept[B_];
    int cnt[EC_] = {0, 0, 0, 0};
    for (int i = 0; i < B_; ++i) used[i] = false;
    for (int i = 0; i < B_; ++i) {
      int best = 0; float bv = -1e30f;
      for (int j = 0; j < B_; ++j)
        if (!used[j] && pcmax[j] > bv) { bv = pcmax[j]; best = j; }
      used[best] = true;
      kept[best] = (++cnt[rc_s[best]] <= CAPN_);
    }
    for (int i = 0; i < B_; ++i)
      eidx[i] = kept[i] ? rc_s[i] : EC_ + ru_s[i];
  }
}

// ---------- GEMM: Y[m][n] = sum_k A[m][k]*Wt[n][k] + bias[n] ----------
// 128x128 tile, BK=64, 256 thr (4 waves of 64x64), XOR-swizzled LDS chunks.
// OMODE 0: bf16 out (QKV; bz==2 writes V directly in Vt chunk layout)
// OMODE 1: fp32 out.
template <int OMODE>
__global__ __launch_bounds__(256) void k_gemm(
    const bf16* __restrict__ A, const bf16* __restrict__ Wt,
    const float* __restrict__ bias0, const float* __restrict__ bias1,
    const float* __restrict__ bias2,
    void* out0, void* out1, void* out2,
    const int* __restrict__ eidx, int mat0) {
  __shared__ __align__(16) char lds[32768];          // A tile 16KB | B tile 16KB
  int bz = blockIdx.z;
  int b = blockIdx.y;
  int e = eidx[b];
  int mtile = blockIdx.x & 3, ntile = blockIdx.x >> 2;
  int m0 = mtile * 128, n0 = ntile * 128;
  const bf16* Ab = A + (size_t)b * S_ * H_;
  const bf16* Wb = Wt + (size_t)((mat0 + bz) * 8 + e) * H_ * H_;
  const float* bias = ((bz == 0) ? bias0 : (bz == 1) ? bias1 : bias2) + (size_t)e * H_;
  void* outp = (bz == 0) ? out0 : (bz == 1) ? out1 : out2;

  int t = threadIdx.x, lane = t & 63, w = t >> 6;
  int wm = (w & 1) * 64, wn = (w >> 1) * 64;
  int lm = lane & 15, lq = lane >> 4;

  floatx4 acc[4][4] = {};
  for (int kt = 0; kt < 12; ++kt) {
    __syncthreads();                                 // protect LDS vs prev iter readers
#pragma unroll
    for (int r = 0; r < 8; ++r) {                    // 2048 chunks of 16B
      int c = t + r * 256;
      const bf16* g;
      if (c < 1024) {
        int mm = c >> 3, pos = c & 7, kc = pos ^ (mm & 7);
        g = Ab + (size_t)(m0 + mm) * H_ + kt * 64 + kc * 8;
      } else {
        int c2 = c - 1024;
        int nn = c2 >> 3, pos = c2 & 7, kc = pos ^ (nn & 7);
        g = Wb + (size_t)(n0 + nn) * H_ + kt * 64 + kc * 8;
      }
      gl_lds16(g, lds + (size_t)c * 16);
    }
    __syncthreads();                                 // vmcnt drained before barrier
#pragma unroll
    for (int kf = 0; kf < 2; ++kf) {
      int kc = kf * 4 + lq;
      short8 af[4], bf[4];
#pragma unroll
      for (int mf = 0; mf < 4; ++mf) {
        int mm = wm + mf * 16 + lm;
        af[mf] = *(const short8*)(lds + ((size_t)(mm * 8 + (kc ^ (mm & 7)))) * 16);
      }
#pragma unroll
      for (int nf = 0; nf < 4; ++nf) {
        int nn = wn + nf * 16 + lm;
        bf[nf] = *(const short8*)(lds + 16384 + ((size_t)(nn * 8 + (kc ^ (nn & 7)))) * 16);
      }
#pragma unroll
      for (int mf = 0; mf < 4; ++mf)
#pragma unroll
        for (int nf = 0; nf < 4; ++nf)
          acc[mf][nf] = __builtin_amdgcn_mfma_f32_16x16x32_bf16(af[mf], bf[nf], acc[mf][nf], 0, 0, 0);
    }
  }
  // epilogue: C/D layout col=lane&15, row=quad*4+reg
#pragma unroll
  for (int mf = 0; mf < 4; ++mf) {
#pragma unroll
    for (int nf = 0; nf < 4; ++nf) {
      int n = n0 + wn + nf * 16 + lm;
      float bv = bias[n];
      int mrow = m0 + wm + mf * 16 + lq * 4;
      size_t rowbase = ((size_t)b * S_ + mrow) * H_ + n;
#pragma unroll
      for (int r = 0; r < 4; ++r) {
        float v = acc[mf][nf][r] + bv;
        if (OMODE == 0) {
          if (bz == 2) {
            // V: write directly in Vt chunk layout [b*NH+h][s>>3][dh][s&7]
            int s = mrow + r;
            ((bf16*)outp)[((size_t)(b * NH_ + (n >> 6))) * 32768 +
                          (size_t)(s >> 3) * 512 + (n & 63) * 8 + (s & 7)] =
                __float2bfloat16(v);
          } else {
            ((bf16*)outp)[rowbase + (size_t)r * H_] = __float2bfloat16(v);
          }
        } else {
          ((float*)outp)[rowbase + (size_t)r * H_] = v;
        }
      }
    }
  }
}

// ---------- attention: one block per (32-row q-tile, h, b); register softmax ----------
__global__ __launch_bounds__(256, 3) void k_attn(
    const bf16* __restrict__ Q, const bf16* __restrict__ K,
    const bf16* __restrict__ Vt, const float* __restrict__ mask,
    bf16* __restrict__ Ctx) {
  __shared__ __align__(16) char bufA[8192];          // K/V tile double buffer
  __shared__ __align__(16) char bufB[8192];
  __shared__ __align__(16) bf16 sc[32 * 520];        // P strip, pad 512->520
  __shared__ float redmax[4][32];
  __shared__ float redsum[4][32];

  int qt = blockIdx.x, h = blockIdx.y, b = blockIdx.z;
  int q0 = qt * 32;
  int t = threadIdx.x, lane = t & 63, w = t >> 6;
  int lm = lane & 15, lq = lane >> 4;

  // Q A-frags directly from global (16B per frag, one-shot)
  short8 qf[2][2];
#pragma unroll
  for (int mf = 0; mf < 2; ++mf)
#pragma unroll
    for (int kf = 0; kf < 2; ++kf)
      qf[mf][kf] = *(const short8*)(Q + ((size_t)(b * S_ + q0 + mf * 16 + lm)) * H_ +
                                    h * DH_ + kf * 32 + lq * 8);
  float mv[8];
#pragma unroll
  for (int kt = 0; kt < 8; ++kt)
    mv[kt] = mask[(size_t)b * S_ + kt * 64 + w * 16 + lm];

  // ---- phase 1: S = QK^T/8 + mask, all 512 cols held in registers ----
  {
#pragma unroll
    for (int r = 0; r < 2; ++r) {                    // stage K tile 0
      int c = t + r * 256, s = c >> 3, pos = c & 7, kc = pos ^ (s & 7);
      gl_lds16(K + ((size_t)(b * S_ + s)) * H_ + h * DH_ + kc * 8, bufA + (size_t)c * 16);
    }
  }
  floatx4 acc[8][2] = {};
  for (int kt = 0; kt < 8; ++kt) {
    __syncthreads();                                 // kt tile ready; prev buffer free
    if (kt < 7) {
      char* nb = ((kt + 1) & 1) ? bufB : bufA;
#pragma unroll
      for (int r = 0; r < 2; ++r) {
        int c = t + r * 256, s = c >> 3, pos = c & 7, kc = pos ^ (s & 7);
        gl_lds16(K + ((size_t)(b * S_ + (kt + 1) * 64 + s)) * H_ + h * DH_ + kc * 8,
                 nb + (size_t)c * 16);
      }
    }
    const char* kb = (kt & 1) ? bufB : bufA;
#pragma unroll
    for (int kf = 0; kf < 2; ++kf) {
      int row = w * 16 + lm, kc = kf * 4 + lq;
      short8 bfr = *(const short8*)(kb + ((size_t)(row * 8 + (kc ^ (row & 7)))) * 16);
#pragma unroll
      for (int mf = 0; mf < 2; ++mf)
        acc[kt][mf] = __builtin_amdgcn_mfma_f32_16x16x32_bf16(qf[mf][kf], bfr, acc[kt][mf], 0, 0, 0);
    }
  }
  __syncthreads();                                   // all waves done with K buffers

  // stage V tile 0 into bufA (overlaps softmax)
  const bf16* vbase = Vt + ((size_t)(b * NH_ + h)) * 64 * 512;
  {
#pragma unroll
    for (int r = 0; r < 2; ++r) {
      int c = t + r * 256;
      gl_lds16(vbase + (size_t)c * 8, bufA + (size_t)c * 16);
    }
  }

  // ---- softmax in registers: rows mf*16+lq*4+r, cols kt*64+w*16+lm ----
  float rmax[2][4];
#pragma unroll
  for (int mf = 0; mf < 2; ++mf)
#pragma unroll
    for (int r = 0; r < 4; ++r) rmax[mf][r] = -1e30f;
#pragma unroll
  for (int kt = 0; kt < 8; ++kt)
#pragma unroll
    for (int mf = 0; mf < 2; ++mf)
#pragma unroll
      for (int r = 0; r < 4; ++r) {
        float s = acc[kt][mf][r] * 0.125f + mv[kt];
        acc[kt][mf][r] = s;
        rmax[mf][r] = fmaxf(rmax[mf][r], s);
      }
#pragma unroll
  for (int st = 1; st < 16; st <<= 1)
#pragma unroll
    for (int mf = 0; mf < 2; ++mf)
#pragma unroll
      for (int r = 0; r < 4; ++r)
        rmax[mf][r] = fmaxf(rmax[mf][r], __shfl_xor(rmax[mf][r], st, 64));
  if (lm == 0) {
#pragma unroll
    for (int mf = 0; mf < 2; ++mf)
#pragma unroll
      for (int r = 0; r < 4; ++r) redmax[w][mf * 16 + lq * 4 + r] = rmax[mf][r];
  }
  __syncthreads();
#pragma unroll
  for (int mf = 0; mf < 2; ++mf)
#pragma unroll
    for (int r = 0; r < 4; ++r) {
      int row = mf * 16 + lq * 4 + r;
      rmax[mf][r] = fmaxf(fmaxf(redmax[0][row], redmax[1][row]),
                          fmaxf(redmax[2][row], redmax[3][row]));
    }
  float rsum[2][4] = {};
#pragma unroll
  for (int kt = 0; kt < 8; ++kt) {
    int col = kt * 64 + w * 16 + lm;
#pragma unroll
    for (int mf = 0; mf < 2; ++mf)
#pragma unroll
      for (int r = 0; r < 4; ++r) {
        float e = __expf(acc[kt][mf][r] - rmax[mf][r]);
        rsum[mf][r] += e;
        sc[(mf * 16 + lq * 4 + r) * 520 + col] = __float2bfloat16(e);
      }
  }
#pragma unroll
  for (int st = 1; st < 16; st <<= 1)
#pragma unroll
    for (int mf = 0; mf < 2; ++mf)
#pragma unroll
      for (int r = 0; r < 4; ++r)
        rsum[mf][r] += __shfl_xor(rsum[mf][r], st, 64);
  if (lm == 0) {
#pragma unroll
    for (int mf = 0; mf < 2; ++mf)
#pragma unroll
      for (int r = 0; r < 4; ++r) redsum[w][mf * 16 + lq * 4 + r] = rsum[mf][r];
  }
  __syncthreads();                                   // P + redsum visible; V0 staged
  float inv[2][4];
#pragma unroll
  for (int mf = 0; mf < 2; ++mf)
#pragma unroll
    for (int r = 0; r < 4; ++r) {
      int row = mf * 16 + lq * 4 + r;
      inv[mf][r] = 1.f / (redsum[0][row] + redsum[1][row] + redsum[2][row] + redsum[3][row]);
    }

  // ---- phase 2: O = P V ----
  floatx4 oacc[2] = {};
  for (int kt = 0; kt < 8; ++kt) {
    if (kt) __syncthreads();
    if (kt < 7) {
      char* nb = ((kt + 1) & 1) ? bufB : bufA;
#pragma unroll
      for (int r = 0; r < 2; ++r) {
        int c = t + r * 256;
        gl_lds16(vbase + ((size_t)((kt + 1) * 512 + c)) * 8, nb + (size_t)c * 16);
      }
    }
    const char* vb = (kt & 1) ? bufB : bufA;
#pragma unroll
    for (int kf = 0; kf < 2; ++kf) {
      int dh = w * 16 + lm;
      short8 bfr = *(const short8*)(vb + ((size_t)((kf * 4 + lq) * 64 + dh)) * 16);
#pragma unroll
      for (int mf = 0; mf < 2; ++mf) {
        int row = mf * 16 + lm;
        short8 af = *(const short8*)((const char*)sc +
                        ((size_t)(row * 520 + kt * 64 + kf * 32 + lq * 8)) * 2);
        oacc[mf] = __builtin_amdgcn_mfma_f32_16x16x32_bf16(af, bfr, oacc[mf], 0, 0, 0);
      }
    }
  }
  int dh = w * 16 + lm;
#pragma unroll
  for (int mf = 0; mf < 2; ++mf)
#pragma unroll
    for (int r = 0; r < 4; ++r) {
      int row = mf * 16 + lq * 4 + r;
      Ctx[((size_t)(b * S_ + q0 + row)) * H_ + h * DH_ + dh] =
          __float2bfloat16(oacc[mf][r] * inv[mf][r]);
    }
}

extern "C" void kernel_launch(void* const* d_in, const int* in_sizes, int n_in,
                              void* d_out, int out_size, void* d_ws, size_t ws_size,
                              hipStream_t stream) {
  const float* X    = (const float*)d_in[0];
  const float* mask = (const float*)d_in[1];
  const float* Wq   = (const float*)d_in[2];
  const float* bq   = (const float*)d_in[3];
  const float* Wk   = (const float*)d_in[4];
  const float* bk   = (const float*)d_in[5];
  const float* Wv   = (const float*)d_in[6];
  const float* bv   = (const float*)d_in[7];
  const float* Wo   = (const float*)d_in[8];
  const float* bo   = (const float*)d_in[9];
  const float* Wsc  = (const float*)d_in[10];
  const float* bsc  = (const float*)d_in[11];
  const float* Wsu  = (const float*)d_in[12];
  const float* bsu  = (const float*)d_in[13];

  char* ws = (char*)d_ws;
  int*   eidx    = (int*)ws;                        //      128 B
  float* partial = (float*)(ws + 256);              //  786,432 B
  float* hmean   = (float*)(ws + 786688);           //   98,304 B
  bf16*  Xh      = (bf16*)(ws + 884992);            // 25,165,824 B
  bf16*  Wt      = (bf16*)(ws + 26050816);          // 37,748,736 B
  bf16*  qb      = (bf16*)(ws + 63799552);          // 25,165,824 B
  bf16*  kb      = (bf16*)(ws + 88965376);          // 25,165,824 B
  bf16*  Vt      = (bf16*)(ws + 139297024);         // 25,165,824 B
  bf16*  ctx     = Xh;                              // alias: Xh dead after QKV GEMM

  k_mean_convert<<<dim3(96, 8), 256, 0, stream>>>(X, Xh, partial);
  k_mean_reduce<<<96, 256, 0, stream>>>(partial, hmean);
  k_wt<<<dim3(24, 24, 32), 256, 0, stream>>>(Wq, Wk, Wv, Wo, Wt);
  k_route<<<1, 256, 0, stream>>>(hmean, Wsc, bsc, Wsu, bsu, eidx);
  k_gemm<0><<<dim3(24, 32, 3), 256, 0, stream>>>(Xh, Wt, bq, bk, bv,
                                                 (void*)qb, (void*)kb, (void*)Vt, eidx, 0);
  k_attn<<<dim3(16, NH_, B_), 256, 0, stream>>>(qb, kb, Vt, mask, ctx);
  k_gemm<1><<<dim3(24, 32, 1), 256, 0, stream>>>(ctx, Wt, bo, bo, bo,
                                                 d_out, d_out, d_out, eidx, 3);
}